// Round 3
// baseline (570.560 us; speedup 1.0000x reference)
//
#include <hip/hip_runtime.h>
#include <stdint.h>

// ---------------------------------------------------------------------------
// Fused 2-layer tanh RNN + FC head for MI355X (gfx950).  Round 3.
//
// B=512,T=1024,I=32,H1=128,H2=64,C=10.  32 blocks x 256 threads (4 waves,
// one per SIMD), 16 batch rows per block; whole serial T-loop in-block.
// Each wave: 2 layer-1 M-tiles (32 ch) AND 1 layer-2 M-tile (16 ch).
// KEY: the b1 fragments read for the l1 recurrence are REUSED as l2's
// input-projection B-operands -> minimal LDS broadcast (24KB reads/step
// vs 56KB in round 2).  One lgkm-only barrier per step.  x prefetch
// distance 4 with compile-time slot rotation; input projection for step
// t+1 computed during step t (off the critical chain).
// Per-step budget: MFMA 64 instr/block = ~310 cyc (4 matrix units),
// LDS ~235 cyc, overlapped -> target ~550-650 cyc/step.
// ---------------------------------------------------------------------------

typedef _Float16 f16x8 __attribute__((ext_vector_type(8)));
typedef float f32x4 __attribute__((ext_vector_type(4)));

#define MFMA_F16(A, B, C) __builtin_amdgcn_mfma_f32_16x16x32_f16((A), (B), (C), 0, 0, 0)

__device__ __forceinline__ float tanh_fast(float x) {
  // tanh(x) = 1 - 2/(1 + 2^(2x*log2e)); abs err ~1e-6.
  float t = __builtin_amdgcn_exp2f(x * 2.88539008177792681472f);
  return 1.0f - 2.0f * __builtin_amdgcn_rcpf(t + 1.0f);
}

__device__ __forceinline__ uint32_t pk16(float a, float b) {
  return __builtin_bit_cast(uint32_t, __builtin_amdgcn_cvt_pkrtz(a, b));
}

// LDS-only barrier: drain ds ops, rendezvous. Leaves global loads in flight.
__device__ __forceinline__ void sync_lds() {
  asm volatile("s_waitcnt lgkmcnt(0)\n\ts_barrier" ::: "memory");
}

__global__ __launch_bounds__(256) void rnn_fused(
    const float* __restrict__ x,
    const float* __restrict__ Wih1, const float* __restrict__ Whh1,
    const float* __restrict__ bih1, const float* __restrict__ bhh1,
    const float* __restrict__ Wih2, const float* __restrict__ Whh2,
    const float* __restrict__ bih2, const float* __restrict__ bhh2,
    const float* __restrict__ Wfc,  const float* __restrict__ bfc,
    float* __restrict__ out)
{
  constexpr int T = 1024, I = 32, H1 = 128, H2 = 64, BB = 16;

  // LDS map (bytes):
  //   H1[0] @ 0      (16 rows x 128 f16 = 4096B)  h1, double-buffered
  //   H1[1] @ 4096
  //   H2[0] @ 8192   (16 rows x  64 f16 = 2048B)  h2_state, double-buffered
  //   H2[1] @ 10240
  //   h2f   @ 12288  (16 rows x  64 f32 = 4096B)  final h2 for FC
  __shared__ __align__(16) unsigned char smem[16384];

  const int tid  = threadIdx.x;
  const int w    = tid >> 6;      // wave 0..3
  const int lane = tid & 63;
  const int g    = lane >> 4;     // k-group 0..3
  const int n    = lane & 15;     // batch col 0..15
  const int b0   = blockIdx.x * BB;

  // ---- zero h1(0) [buf0] and h2_state(0) [buf0] ----
  {
    uint32_t* p = (uint32_t*)smem;
    for (int i = tid; i < 1024; i += 256) p[i] = 0u;          // H1[0]
    uint32_t* q = (uint32_t*)(smem + 8192);
    for (int i = tid; i < 512; i += 256) q[i] = 0u;           // H2[0]
  }

  // f32 weights -> fp16 A-fragment (8 consecutive k's of one channel row)
  auto cvt8 = [](const float* s) -> f16x8 {
    f32x4 a = *(const f32x4*)s;
    f32x4 b = *(const f32x4*)(s + 4);
    f16x8 r;
#pragma unroll
    for (int j = 0; j < 4; ++j) { r[j] = (_Float16)a[j]; r[4 + j] = (_Float16)b[j]; }
    return r;
  };

  // ---- weights -> register A-fragments, loaded once ----
  f16x8 aU[2][4];   // W_hh1 for l1 tiles {2w, 2w+1}
  f16x8 aI1[2];     // W_ih1 (K=32 -> one k-step per tile)
  f16x8 aI2[4];     // W_ih2 for l2 tile w (K=128)
  f16x8 aR2[2];     // W_hh2 (K=64)
#pragma unroll
  for (int ti = 0; ti < 2; ++ti) {
    const int ch = (2 * w + ti) * 16 + n;
#pragma unroll
    for (int k4 = 0; k4 < 4; ++k4)
      aU[ti][k4] = cvt8(Whh1 + ch * H1 + k4 * 32 + g * 8);
    aI1[ti] = cvt8(Wih1 + ch * I + g * 8);
  }
  {
    const int ch2 = w * 16 + n;
#pragma unroll
    for (int k4 = 0; k4 < 4; ++k4)
      aI2[k4] = cvt8(Wih2 + ch2 * H1 + k4 * 32 + g * 8);
#pragma unroll
    for (int k2 = 0; k2 < 2; ++k2)
      aR2[k2] = cvt8(Whh2 + ch2 * H2 + k2 * 32 + g * 8);
  }

  // Biases in the MFMA C layout: col=lane&15, row=(lane>>4)*4+r.
  f32x4 bias1[2], bias2;
#pragma unroll
  for (int ti = 0; ti < 2; ++ti) {
    const int ch = (2 * w + ti) * 16 + g * 4;
#pragma unroll
    for (int r = 0; r < 4; ++r) bias1[ti][r] = bih1[ch + r] + bhh1[ch + r];
  }
  {
    const int ch2 = w * 16 + g * 4;
#pragma unroll
    for (int r = 0; r < 4; ++r) bias2[r] = bih2[ch2 + r] + bhh2[ch2 + r];
  }

  // ---- per-lane LDS byte offsets, 16B-slot XOR swizzle (slot ^= n&7) ----
  int roff1[4], roff2[2], woff1[2], woff2;
#pragma unroll
  for (int k4 = 0; k4 < 4; ++k4)
    roff1[k4] = n * 256 + (((k4 * 4 + g) ^ (n & 7)) << 4);
#pragma unroll
  for (int k2 = 0; k2 < 2; ++k2)
    roff2[k2] = n * 128 + (((k2 * 4 + g) ^ (n & 7)) << 4);
#pragma unroll
  for (int ti = 0; ti < 2; ++ti) {
    const int tt = 2 * w + ti;
    woff1[ti] = n * 256 + (((2 * tt + (g >> 1)) ^ (n & 7)) << 4) + (g & 1) * 8;
  }
  woff2 = n * 128 + (((2 * w + (g >> 1)) ^ (n & 7)) << 4) + (g & 1) * 8;

  __syncthreads();  // zero-init visible (once; vmcnt drain harmless here)

  // ---- x queue: 4 slots (prefetch distance 4), compile-time rotation ----
  const float* xp = x + (size_t)(b0 + n) * T * I + g * 8;
  f32x4 q0a = *(const f32x4*)(xp + 0 * I), q0b = *(const f32x4*)(xp + 0 * I + 4);
  f32x4 q1a = *(const f32x4*)(xp + 1 * I), q1b = *(const f32x4*)(xp + 1 * I + 4);
  f32x4 q2a = *(const f32x4*)(xp + 2 * I), q2b = *(const f32x4*)(xp + 2 * I + 4);
  f32x4 q3a = *(const f32x4*)(xp + 3 * I), q3b = *(const f32x4*)(xp + 3 * I + 4);

  auto pack_x = [&](const f32x4& a, const f32x4& b) -> f16x8 {
    union { uint32_t u[4]; f16x8 v; } tmp;
    tmp.u[0] = pk16(a[0], a[1]); tmp.u[1] = pk16(a[2], a[3]);
    tmp.u[2] = pk16(b[0], b[1]); tmp.u[3] = pk16(b[2], b[3]);
    return tmp.v;
  };

  // input projection for step 0 (C-init of the l1 recurrent chains)
  f32x4 accI0, accI1;
  {
    f16x8 xf = pack_x(q0a, q0b);
    accI0 = MFMA_F16(aI1[0], xf, bias1[0]);
    accI1 = MFMA_F16(aI1[1], xf, bias1[1]);
  }

  auto tanh_pack = [&](const f32x4& a, uint32_t& lo, uint32_t& hi) {
    lo = pk16(tanh_fast(a[0]), tanh_fast(a[1]));
    hi = pk16(tanh_fast(a[2]), tanh_fast(a[3]));
  };

  // One fused timestep; cur = t&1 is compile-time at each call site.
  // Iter t: l1 computes h1(t+1); l2 (t>0) computes h2_state(t) from
  // h1(t)=out1[t-1] (the SAME b1 frags) and h2_state(t-1).
  auto step = [&](int t, int cur, f32x4& la, f32x4& lb,
                  const f32x4& pa, const f32x4& pb) {
    const char* H1c = (const char*)smem + cur * 4096;              // h1(t)
    char*       H1n = (char*)smem + (cur ^ 1) * 4096;              // h1(t+1)
    const char* H2r = (const char*)smem + 8192 + (cur ^ 1) * 2048; // h2s(t-1)
    char*       H2w = (char*)smem + 8192 + cur * 2048;             // h2s(t)

    // shared-state fragment reads
    f16x8 b1k0 = *(const f16x8*)(H1c + roff1[0]);
    f16x8 b1k1 = *(const f16x8*)(H1c + roff1[1]);
    f16x8 b1k2 = *(const f16x8*)(H1c + roff1[2]);
    f16x8 b1k3 = *(const f16x8*)(H1c + roff1[3]);
    f16x8 b2k0 = *(const f16x8*)(H2r + roff2[0]);
    f16x8 b2k1 = *(const f16x8*)(H2r + roff2[1]);

    // prefetch x(t+4) into the just-consumed slot
    if (t + 4 < T) {
      la = *(const f32x4*)(xp + (t + 4) * I);
      lb = *(const f32x4*)(xp + (t + 4) * I + 4);
    }

    // ---- layer 1: two M-tiles, two 2-deep accumulator chains each ----
    f32x4 zero = {0.f, 0.f, 0.f, 0.f};
    f32x4 aA0 = MFMA_F16(aU[0][0], b1k0, accI0);
    f32x4 aB0 = MFMA_F16(aU[0][2], b1k2, zero);
    f32x4 aA1 = MFMA_F16(aU[1][0], b1k0, accI1);
    f32x4 aB1 = MFMA_F16(aU[1][2], b1k2, zero);
    aA0 = MFMA_F16(aU[0][1], b1k1, aA0);
    aB0 = MFMA_F16(aU[0][3], b1k3, aB0);
    aA1 = MFMA_F16(aU[1][1], b1k1, aA1);
    aB1 = MFMA_F16(aU[1][3], b1k3, aB1);

    // ---- layer 2 (reuses b1 frags): three 2-deep chains ----
    f32x4 cA, cB, cC;
    const bool do_l2 = (t > 0);
    if (do_l2) {
      cA = MFMA_F16(aI2[0], b1k0, bias2);
      cB = MFMA_F16(aI2[1], b1k1, zero);
      cC = MFMA_F16(aR2[0], b2k0, zero);
      cA = MFMA_F16(aI2[2], b1k2, cA);
      cB = MFMA_F16(aI2[3], b1k3, cB);
      cC = MFMA_F16(aR2[1], b2k1, cC);
    }

    // next step's input projection (off the critical chain)
    {
      f16x8 xf = pack_x(pa, pb);
      accI0 = MFMA_F16(aI1[0], xf, bias1[0]);
      accI1 = MFMA_F16(aI1[1], xf, bias1[1]);
    }

    // l1 epilogue: tanh -> fp16 -> LDS next buffer
    {
      f32x4 s0 = aA0 + aB0, s1 = aA1 + aB1;
      uint32_t lo, hi;
      tanh_pack(s0, lo, hi);
      *(uint2*)(H1n + woff1[0]) = make_uint2(lo, hi);
      tanh_pack(s1, lo, hi);
      *(uint2*)(H1n + woff1[1]) = make_uint2(lo, hi);
    }
    // l2 epilogue
    if (do_l2) {
      f32x4 s2 = cA + cB + cC;
      uint32_t lo, hi;
      tanh_pack(s2, lo, hi);
      *(uint2*)(H2w + woff2) = make_uint2(lo, hi);
    }

    sync_lds();  // the ONE barrier per timestep (lgkm only)
  };

  for (int t = 0; t < T; t += 4) {
    step(t + 0, 0, q0a, q0b, q1a, q1b);
    step(t + 1, 1, q1a, q1b, q2a, q2b);
    step(t + 2, 0, q2a, q2b, q3a, q3b);
    step(t + 3, 1, q3a, q3b, q0a, q0b);
  }

  // ---- final l2 step: h2_state(T) from h1(T) [buf0] + h2_state(T-1) [buf1]
  {
    const char* H1c = (const char*)smem;                 // h1(1024)
    const char* H2r = (const char*)smem + 8192 + 2048;   // h2_state(1023)
    f16x8 b1k0 = *(const f16x8*)(H1c + roff1[0]);
    f16x8 b1k1 = *(const f16x8*)(H1c + roff1[1]);
    f16x8 b1k2 = *(const f16x8*)(H1c + roff1[2]);
    f16x8 b1k3 = *(const f16x8*)(H1c + roff1[3]);
    f16x8 b2k0 = *(const f16x8*)(H2r + roff2[0]);
    f16x8 b2k1 = *(const f16x8*)(H2r + roff2[1]);
    f32x4 zero = {0.f, 0.f, 0.f, 0.f};
    f32x4 cA = MFMA_F16(aI2[0], b1k0, bias2);
    f32x4 cB = MFMA_F16(aI2[1], b1k1, zero);
    f32x4 cC = MFMA_F16(aR2[0], b2k0, zero);
    cA = MFMA_F16(aI2[2], b1k2, cA);
    cB = MFMA_F16(aI2[3], b1k3, cB);
    cC = MFMA_F16(aR2[1], b2k1, cC);
    f32x4 s = cA + cB + cC;
    f32x4 hv;
#pragma unroll
    for (int r = 0; r < 4; ++r) hv[r] = tanh_fast(s[r]);
    // f32 h2 final, linear layout [n][ch] for the FC head
    *(f32x4*)(smem + 12288 + n * 256 + (16 * w + 4 * g) * 4) = hv;
  }
  sync_lds();

  // ---- FC head: logits[b][c] = b_fc[c] + sum_k h2f[b][k] * Wfc[c][k] ----
  if (tid < BB * 10) {
    const int b = tid / 10, c = tid % 10;
    const float* hrow = (const float*)(smem + 12288 + b * 256);
    float acc = bfc[c];
#pragma unroll 8
    for (int k = 0; k < 64; ++k) acc += hrow[k] * Wfc[c * 64 + k];
    out[(size_t)(b0 + b) * 10 + c] = acc;
  }
}

extern "C" void kernel_launch(void* const* d_in, const int* in_sizes, int n_in,
                              void* d_out, int out_size, void* d_ws, size_t ws_size,
                              hipStream_t stream) {
  const float* x    = (const float*)d_in[0];
  const float* Wih1 = (const float*)d_in[1];
  const float* Whh1 = (const float*)d_in[2];
  const float* bih1 = (const float*)d_in[3];
  const float* bhh1 = (const float*)d_in[4];
  const float* Wih2 = (const float*)d_in[5];
  const float* Whh2 = (const float*)d_in[6];
  const float* bih2 = (const float*)d_in[7];
  const float* bhh2 = (const float*)d_in[8];
  const float* Wfc  = (const float*)d_in[9];
  const float* bfc  = (const float*)d_in[10];

  hipLaunchKernelGGL(rnn_fused, dim3(512 / 16), dim3(256), 0, stream,
                     x, Wih1, Whh1, bih1, bhh1, Wih2, Whh2, bih2, bhh2,
                     Wfc, bfc, (float*)d_out);
}

// Round 4
// 471.684 us; speedup vs baseline: 1.2096x; 1.2096x over previous
//
#include <hip/hip_runtime.h>
#include <stdint.h>

// ---------------------------------------------------------------------------
// Fused 2-layer tanh RNN + FC head for MI355X (gfx950).  Round 4.
//
// B=512,T=1024,I=32,H1=128,H2=64,C=10.  32 blocks x 512 threads (8 waves),
// 16 batch rows per block; whole serial T-loop in-block.
// ROLE SPLIT: waves 0-3 = layer-1 (2 M-tiles = 32 ch each); waves 4-7 =
// layer-2 (1 M-tile = 16 ch each, lagged one step).  Each SIMD hosts one
// l1-wave + one l2-wave -> per-step tanh/VALU issue is split across the
// two waves and interleaved by the HW scheduler, instead of serialized
// on a single wave per SIMD (rounds 1-3's structural limit).
// LDS rows PADDED to 272B (h1) / 144B (h2): all ds accesses <=2-way
// (2-way is free, m136) -- fixes round-1..3's systematic conflicts.
// One lgkm-only barrier per step; x prefetch dist 4; input projection
// for step t+1 computed during step t.
// ---------------------------------------------------------------------------

typedef _Float16 f16x8 __attribute__((ext_vector_type(8)));
typedef float f32x4 __attribute__((ext_vector_type(4)));

#define MFMA_F16(A, B, C) __builtin_amdgcn_mfma_f32_16x16x32_f16((A), (B), (C), 0, 0, 0)

__device__ __forceinline__ float tanh_fast(float x) {
  // tanh(x) = 1 - 2/(1 + 2^(2x*log2e)); abs err ~1e-6.
  float t = __builtin_amdgcn_exp2f(x * 2.88539008177792681472f);
  return 1.0f - 2.0f * __builtin_amdgcn_rcpf(t + 1.0f);
}

__device__ __forceinline__ uint32_t pk16(float a, float b) {
  return __builtin_bit_cast(uint32_t, __builtin_amdgcn_cvt_pkrtz(a, b));
}

// LDS-only barrier: drain ds ops, rendezvous. Leaves global loads in flight.
__device__ __forceinline__ void sync_lds() {
  asm volatile("s_waitcnt lgkmcnt(0)\n\ts_barrier" ::: "memory");
}

__global__ __launch_bounds__(512) void rnn_fused(
    const float* __restrict__ x,
    const float* __restrict__ Wih1, const float* __restrict__ Whh1,
    const float* __restrict__ bih1, const float* __restrict__ bhh1,
    const float* __restrict__ Wih2, const float* __restrict__ Whh2,
    const float* __restrict__ bih2, const float* __restrict__ bhh2,
    const float* __restrict__ Wfc,  const float* __restrict__ bfc,
    float* __restrict__ out)
{
  constexpr int T = 1024, I = 32, H1 = 128, H2 = 64, BB = 16;
  // Padded LDS row strides: 272B = 17*16 (h1), 144B = 9*16 (h2).
  // bank(byte) = (byte/4)%32; n*272 == n*4 (mod 128B) -> reads/writes <=2-way.
  constexpr int R1 = 272, R2 = 144;
  constexpr int H1_0 = 0, H1_1 = 4352;          // 16*272 each
  constexpr int H2_0 = 8704, H2_1 = 11008;      // 16*144 each
  constexpr int H2F  = 13312;                   // 16 rows x 256B f32
  __shared__ __align__(16) unsigned char smem[17408];

  const int tid  = threadIdx.x;
  const int w    = tid >> 6;      // wave 0..7
  const int lane = tid & 63;
  const int g    = lane >> 4;     // k-group 0..3
  const int n    = lane & 15;     // batch col 0..15
  const int b0   = blockIdx.x * BB;

  // ---- zero h1(0) and h2(0) (whole padded buffers) ----
  {
    uint32_t* p = (uint32_t*)smem;
    for (int i = tid; i < 1088; i += 512) p[i] = 0u;          // H1[0]
    uint32_t* q = (uint32_t*)(smem + H2_0);
    for (int i = tid; i < 576; i += 512) q[i] = 0u;           // H2[0]
  }

  auto cvt8 = [](const float* s) -> f16x8 {
    f32x4 a = *(const f32x4*)s;
    f32x4 b = *(const f32x4*)(s + 4);
    f16x8 r;
#pragma unroll
    for (int j = 0; j < 4; ++j) { r[j] = (_Float16)a[j]; r[4 + j] = (_Float16)b[j]; }
    return r;
  };

  // h1 B-frag read offsets (common to both roles): k = k4*32 + g*8.
  int roff1[4];
#pragma unroll
  for (int k4 = 0; k4 < 4; ++k4)
    roff1[k4] = n * R1 + k4 * 64 + g * 16;

  auto tanh_pack = [&](const f32x4& a, uint32_t& lo, uint32_t& hi) {
    lo = pk16(tanh_fast(a[0]), tanh_fast(a[1]));
    hi = pk16(tanh_fast(a[2]), tanh_fast(a[3]));
  };

  __syncthreads();  // zero-init visible (vmcnt drain harmless, once)

  const f32x4 zero = {0.f, 0.f, 0.f, 0.f};

  if (w < 4) {
    // ============ layer-1 wave: tiles {2w, 2w+1} = channels 32w..32w+31 ====
    f16x8 aU[2][4], aI1[2];
    f32x4 bias1[2];
#pragma unroll
    for (int ti = 0; ti < 2; ++ti) {
      const int ch = (2 * w + ti) * 16 + n;
#pragma unroll
      for (int k4 = 0; k4 < 4; ++k4)
        aU[ti][k4] = cvt8(Whh1 + ch * H1 + k4 * 32 + g * 8);
      aI1[ti] = cvt8(Wih1 + ch * I + g * 8);
      const int cb = (2 * w + ti) * 16 + g * 4;
#pragma unroll
      for (int r = 0; r < 4; ++r) bias1[ti][r] = bih1[cb + r] + bhh1[cb + r];
    }
    // D-write offsets: lane (g,n) holds rows 4g..4g+3 of tile tt -> 8B write.
    int woff[2];
#pragma unroll
    for (int ti = 0; ti < 2; ++ti)
      woff[ti] = n * R1 + (2 * w + ti) * 32 + g * 8;

    const float* xp = x + (size_t)(b0 + n) * T * I + g * 8;
    // x queue: 4 slots (dist 4), compile-time rotation.
    f32x4 q0a = *(const f32x4*)(xp + 0 * I), q0b = *(const f32x4*)(xp + 0 * I + 4);
    f32x4 q1a = *(const f32x4*)(xp + 1 * I), q1b = *(const f32x4*)(xp + 1 * I + 4);
    f32x4 q2a = *(const f32x4*)(xp + 2 * I), q2b = *(const f32x4*)(xp + 2 * I + 4);
    f32x4 q3a = *(const f32x4*)(xp + 3 * I), q3b = *(const f32x4*)(xp + 3 * I + 4);

    auto pack_x = [&](const f32x4& a, const f32x4& b) -> f16x8 {
      union { uint32_t u[4]; f16x8 v; } tmp;
      tmp.u[0] = pk16(a[0], a[1]); tmp.u[1] = pk16(a[2], a[3]);
      tmp.u[2] = pk16(b[0], b[1]); tmp.u[3] = pk16(b[2], b[3]);
      return tmp.v;
    };

    f32x4 accI0, accI1;
    {
      f16x8 xf = pack_x(q0a, q0b);
      accI0 = MFMA_F16(aI1[0], xf, bias1[0]);
      accI1 = MFMA_F16(aI1[1], xf, bias1[1]);
    }

    auto stepL1 = [&](int t, int cur, f32x4& la, f32x4& lb,
                      const f32x4& pa, const f32x4& pb) {
      const char* H1c = (const char*)smem + (cur ? H1_1 : H1_0);
      char*       H1n = (char*)smem + (cur ? H1_0 : H1_1);
      f16x8 b1k0 = *(const f16x8*)(H1c + roff1[0]);
      f16x8 b1k1 = *(const f16x8*)(H1c + roff1[1]);
      f16x8 b1k2 = *(const f16x8*)(H1c + roff1[2]);
      f16x8 b1k3 = *(const f16x8*)(H1c + roff1[3]);
      if (t + 4 < T) {  // prefetch x(t+4) into the just-consumed slot
        la = *(const f32x4*)(xp + (t + 4) * I);
        lb = *(const f32x4*)(xp + (t + 4) * I + 4);
      }
      // two 2-deep chains per tile
      f32x4 aA0 = MFMA_F16(aU[0][0], b1k0, accI0);
      f32x4 aB0 = MFMA_F16(aU[0][2], b1k2, zero);
      f32x4 aA1 = MFMA_F16(aU[1][0], b1k0, accI1);
      f32x4 aB1 = MFMA_F16(aU[1][2], b1k2, zero);
      aA0 = MFMA_F16(aU[0][1], b1k1, aA0);
      aB0 = MFMA_F16(aU[0][3], b1k3, aB0);
      aA1 = MFMA_F16(aU[1][1], b1k1, aA1);
      aB1 = MFMA_F16(aU[1][3], b1k3, aB1);
      // next step's input projection (off the critical chain)
      {
        f16x8 xf = pack_x(pa, pb);
        accI0 = MFMA_F16(aI1[0], xf, bias1[0]);
        accI1 = MFMA_F16(aI1[1], xf, bias1[1]);
      }
      // early write tile 0, then tile 1
      {
        f32x4 s0 = aA0 + aB0;
        uint32_t lo, hi;
        tanh_pack(s0, lo, hi);
        *(uint2*)(H1n + woff[0]) = make_uint2(lo, hi);
      }
      {
        f32x4 s1 = aA1 + aB1;
        uint32_t lo, hi;
        tanh_pack(s1, lo, hi);
        *(uint2*)(H1n + woff[1]) = make_uint2(lo, hi);
      }
      sync_lds();
    };

    for (int t = 0; t < T; t += 4) {
      stepL1(t + 0, 0, q0a, q0b, q1a, q1b);
      stepL1(t + 1, 1, q1a, q1b, q2a, q2b);
      stepL1(t + 2, 0, q2a, q2b, q3a, q3b);
      stepL1(t + 3, 1, q3a, q3b, q0a, q0b);
    }
  } else {
    // ============ layer-2 wave: tile j = w-4, channels 16j..16j+15 =========
    const int j = w - 4;
    f16x8 aI2[4], aR2[2];
#pragma unroll
    for (int k4 = 0; k4 < 4; ++k4)
      aI2[k4] = cvt8(Wih2 + (16 * j + n) * H1 + k4 * 32 + g * 8);
#pragma unroll
    for (int k2 = 0; k2 < 2; ++k2)
      aR2[k2] = cvt8(Whh2 + (16 * j + n) * H2 + k2 * 32 + g * 8);
    f32x4 bias2;
#pragma unroll
    for (int r = 0; r < 4; ++r) bias2[r] = bih2[16 * j + g * 4 + r] + bhh2[16 * j + g * 4 + r];

    int roff2[2];
#pragma unroll
    for (int k2 = 0; k2 < 2; ++k2)
      roff2[k2] = n * R2 + k2 * 64 + g * 16;
    const int woff2 = n * R2 + j * 32 + g * 8;

    auto l2_body = [&](const char* H1c, const char* H2r, f32x4& s) {
      f16x8 b1k0 = *(const f16x8*)(H1c + roff1[0]);
      f16x8 b1k1 = *(const f16x8*)(H1c + roff1[1]);
      f16x8 b1k2 = *(const f16x8*)(H1c + roff1[2]);
      f16x8 b1k3 = *(const f16x8*)(H1c + roff1[3]);
      f16x8 b2k0 = *(const f16x8*)(H2r + roff2[0]);
      f16x8 b2k1 = *(const f16x8*)(H2r + roff2[1]);
      f32x4 cA = MFMA_F16(aI2[0], b1k0, bias2);
      f32x4 cB = MFMA_F16(aI2[1], b1k1, zero);
      f32x4 cC = MFMA_F16(aR2[0], b2k0, zero);
      cA = MFMA_F16(aI2[2], b1k2, cA);
      cB = MFMA_F16(aI2[3], b1k3, cB);
      cC = MFMA_F16(aR2[1], b2k1, cC);
      s = cA + cB + cC;
    };

    auto stepL2 = [&](int t, int cur) {
      if (t > 0) {
        const char* H1c = (const char*)smem + (cur ? H1_1 : H1_0);     // h1(t)
        const char* H2r = (const char*)smem + (cur ? H2_0 : H2_1);     // h2(t-1)
        char*       H2w = (char*)smem + (cur ? H2_1 : H2_0);           // h2(t)
        f32x4 s;
        l2_body(H1c, H2r, s);
        uint32_t lo, hi;
        tanh_pack(s, lo, hi);
        *(uint2*)(H2w + woff2) = make_uint2(lo, hi);
      }
      sync_lds();
    };

    for (int t = 0; t < T; t += 2) {
      stepL2(t + 0, 0);
      stepL2(t + 1, 1);
    }

    // final step: h2(T) from h1(T) [H1_0] and h2(T-1) [H2_1]
    {
      f32x4 s;
      l2_body((const char*)smem + H1_0, (const char*)smem + H2_1, s);
      f32x4 hv;
#pragma unroll
      for (int r = 0; r < 4; ++r) hv[r] = tanh_fast(s[r]);
      // f32 final h2, linear [n][ch] rows of 256B for the FC head
      *(f32x4*)(smem + H2F + n * 256 + (16 * j + 4 * g) * 4) = hv;
    }
  }

  sync_lds();  // h2f visible to all (l1 waves arrive here after their loop)

  // ---- FC head: logits[b][c] = b_fc[c] + sum_k h2f[b][k] * Wfc[c][k] ----
  if (tid < BB * 10) {
    const int b = tid / 10, c = tid % 10;
    const float* hrow = (const float*)(smem + H2F + b * 256);
    float acc = bfc[c];
#pragma unroll 8
    for (int k = 0; k < 64; ++k) acc += hrow[k] * Wfc[c * 64 + k];
    out[(size_t)(b0 + b) * 10 + c] = acc;
  }
}

extern "C" void kernel_launch(void* const* d_in, const int* in_sizes, int n_in,
                              void* d_out, int out_size, void* d_ws, size_t ws_size,
                              hipStream_t stream) {
  const float* x    = (const float*)d_in[0];
  const float* Wih1 = (const float*)d_in[1];
  const float* Whh1 = (const float*)d_in[2];
  const float* bih1 = (const float*)d_in[3];
  const float* bhh1 = (const float*)d_in[4];
  const float* Wih2 = (const float*)d_in[5];
  const float* Whh2 = (const float*)d_in[6];
  const float* bih2 = (const float*)d_in[7];
  const float* bhh2 = (const float*)d_in[8];
  const float* Wfc  = (const float*)d_in[9];
  const float* bfc  = (const float*)d_in[10];

  hipLaunchKernelGGL(rnn_fused, dim3(512 / 16), dim3(512), 0, stream,
                     x, Wih1, Whh1, bih1, bhh1, Wih2, Whh2, bih2, bhh2,
                     Wfc, bfc, (float*)d_out);
}